// Round 17
// baseline (70.616 us; speedup 1.0000x reference)
//
#include <hip/hip_runtime.h>
#include <hip/hip_bf16.h>
#include <math.h>
#include <stdint.h>

#define N_RAYS    32768
#define N_SAMPLES (N_RAYS * 32)
#define THRESH 0.0001f
#define RPB    8                         // rays per block (contiguous samples)
#define MAXS   464                       // max samples per block (8*57=456)

// record ids in frag table (one uint4 per lane per record)
#define R_A1   0   // +t (2)
#define R_A2   2   // +c (4)
#define R_R1A  6   // +2t+c (4)
#define R_R1B  10  // +t (2)
#define R_AR2  12  // +c (4)
#define R_AR2F 16  // +c (2)
#define R_B2I  18  // +i (4)
#define R_ARI  22  // +i (4)
#define NREC   26

typedef __attribute__((ext_vector_type(8)))  __bf16 bf16x8;
typedef __attribute__((ext_vector_type(16))) float  f32x16;
typedef float f4a __attribute__((ext_vector_type(4), aligned(4)));

union FragU  { __hip_bfloat162 h2[4]; uint32_t w[4]; bf16x8 v; };
union RecU   { bf16x8 v; uint4 u; };
union Rec16U { f32x16 v; uint4 u[4]; float f[16]; };

__device__ inline __hip_bfloat162 pk2(float lo, float hi) {
    float2 t; t.x = lo; t.y = hi;
    return __float22bfloat162_rn(t);
}

__device__ inline bf16x8 pack8(const float* vals) {
    FragU u;
    u.h2[0] = pk2(vals[0], vals[1]);
    u.h2[1] = pk2(vals[2], vals[3]);
    u.h2[2] = pk2(vals[4], vals[5]);
    u.h2[3] = pk2(vals[6], vals[7]);
    return u.v;
}

__device__ inline float rcp_fast(float x) {
    float r;
    asm("v_rcp_f32 %0, %1" : "=v"(r) : "v"(x));
    return r;
}
__device__ inline float sigmoid_fast(float x) { return rcp_fast(1.0f + __expf(-x)); }
__device__ inline float softplus_fast(float x) {
    const float e = __expf(-fabsf(x));
    return fmaxf(x, 0.0f) + __logf(1.0f + e);
}

template <int P>
__device__ inline bf16x8 packB_relu(f32x16 a) {
    FragU u;
    u.h2[0] = pk2(fmaxf(a[P+0],0.f), fmaxf(a[P+1],0.f));
    u.h2[1] = pk2(fmaxf(a[P+2],0.f), fmaxf(a[P+3],0.f));
    u.h2[2] = pk2(fmaxf(a[P+4],0.f), fmaxf(a[P+5],0.f));
    u.h2[3] = pk2(fmaxf(a[P+6],0.f), fmaxf(a[P+7],0.f));
    return u.v;
}
template <int P>
__device__ inline bf16x8 packB_relu2(f32x16 x, f32x16 y) {
    FragU u;
    u.h2[0] = pk2(fmaxf(x[P+0]+y[P+0],0.f), fmaxf(x[P+1]+y[P+1],0.f));
    u.h2[1] = pk2(fmaxf(x[P+2]+y[P+2],0.f), fmaxf(x[P+3]+y[P+3],0.f));
    u.h2[2] = pk2(fmaxf(x[P+4]+y[P+4],0.f), fmaxf(x[P+5]+y[P+5],0.f));
    u.h2[3] = pk2(fmaxf(x[P+6]+y[P+6],0.f), fmaxf(x[P+7]+y[P+7],0.f));
    return u.v;
}
template <int P>
__device__ inline bf16x8 packB_plain2(f32x16 x, f32x16 y) {
    FragU u;
    u.h2[0] = pk2(x[P+0]+y[P+0], x[P+1]+y[P+1]);
    u.h2[1] = pk2(x[P+2]+y[P+2], x[P+3]+y[P+3]);
    u.h2[2] = pk2(x[P+4]+y[P+4], x[P+5]+y[P+5]);
    u.h2[3] = pk2(x[P+6]+y[P+6], x[P+7]+y[P+7]);
    return u.v;
}

// ---------------------------------------------------------------------------
// Setup kernel: per-lane weight fragments for the 32x32x16 path (identical to
// rounds 12-16 — layout verified). D layout: col=lane&31,
// row=(reg&3)+8*(reg>>2)+4*(lane>>5);  rr(q,h) = (q&3)+8*(q>>2)+4*h.
// ---------------------------------------------------------------------------
__global__ __launch_bounds__(256) void nerf_build_frags(
    const float* __restrict__ w1,  const float* __restrict__ b1,
    const float* __restrict__ w2,  const float* __restrict__ b2,
    const float* __restrict__ w_sigma, const float* __restrict__ b_sigma,
    const float* __restrict__ w_rgb1,  const float* __restrict__ b_rgb1,
    const float* __restrict__ w_rgb2,  const float* __restrict__ b_rgb2,
    uint4* __restrict__ tbl)
{
    const int wid  = threadIdx.x >> 6;
    const int lane = threadIdx.x & 63;
    const int m    = lane & 31;
    const int h    = lane >> 5;
    RecU rec;

    if (wid == 0) {
        #pragma unroll
        for (int t = 0; t < 2; ++t) {        // A1: rows j=32t+m; k slots h=0,q0..3
            float v[8] = {0,0,0,0,0,0,0,0};
            if (h == 0) {
                const int j = 32*t + m;
                v[0] = w1[j]; v[1] = w1[64+j]; v[2] = w1[128+j]; v[3] = b1[j];
            }
            rec.v = pack8(v); tbl[(R_A1+t)*64 + lane] = rec.u;
        }
        #pragma unroll
        for (int c = 0; c < 4; ++c) {        // A2: A[f=m][j=16c+rr(q,h)] = w2[j*32+f]
            float v[8];
            #pragma unroll
            for (int q = 0; q < 8; ++q) {
                const int j = 16*c + (q&3) + 8*(q>>2) + 4*h;
                v[q] = w2[j*32 + m];
            }
            rec.v = pack8(v); tbl[(R_A2+c)*64 + lane] = rec.u;
        }
    } else if (wid == 1) {
        #pragma unroll
        for (int t = 0; t < 2; ++t)          // Ar1a: rows j=32t+m; k=f=16c+rr
            #pragma unroll
            for (int c = 0; c < 2; ++c) {
                float v[8];
                #pragma unroll
                for (int q = 0; q < 8; ++q) {
                    const int f = 16*c + (q&3) + 8*(q>>2) + 4*h;
                    v[q] = w_rgb1[f*64 + 32*t + m];
                }
                rec.v = pack8(v); tbl[(R_R1A+2*t+c)*64 + lane] = rec.u;
            }
        #pragma unroll
        for (int t = 0; t < 2; ++t) {        // Ar1b: dirs+bias on h=1 slots q0..3
            float v[8] = {0,0,0,0,0,0,0,0};
            if (h == 1) {
                const int j = 32*t + m;
                v[0] = w_rgb1[32*64 + j]; v[1] = w_rgb1[33*64 + j];
                v[2] = w_rgb1[34*64 + j]; v[3] = b_rgb1[j];
            }
            rec.v = pack8(v); tbl[(R_R1B+t)*64 + lane] = rec.u;
        }
    } else if (wid == 2) {
        #pragma unroll
        for (int c = 0; c < 4; ++c) {        // Ar2: rows m=0..2 rgb; k=hh=16c+rr
            float v[8];
            #pragma unroll
            for (int q = 0; q < 8; ++q) {
                const int hh = 16*c + (q&3) + 8*(q>>2) + 4*h;
                v[q] = (m < 3) ? w_rgb2[hh*3 + m] : 0.0f;
            }
            rec.v = pack8(v); tbl[(R_AR2+c)*64 + lane] = rec.u;
        }
        #pragma unroll
        for (int c = 0; c < 2; ++c) {        // Ar2f: w_sigma on row m=3; k=f=16c+rr
            float v[8];
            #pragma unroll
            for (int q = 0; q < 8; ++q) {
                const int f = 16*c + (q&3) + 8*(q>>2) + 4*h;
                v[q] = (m == 3) ? w_sigma[f] : 0.0f;
            }
            rec.v = pack8(v); tbl[(R_AR2F+c)*64 + lane] = rec.u;
        }
        Rec16U r16;
        #pragma unroll
        for (int i = 0; i < 4; ++i) {        // b2i: C-init, reg=4i+e -> b2[e+8i+4h]
            #pragma unroll
            for (int e = 0; e < 4; ++e) r16.f[4*i+e] = b2[e + 8*i + 4*h];
        }
        #pragma unroll
        for (int i = 0; i < 4; ++i) tbl[(R_B2I+i)*64 + lane] = r16.u[i];
        #pragma unroll
        for (int i = 0; i < 4; ++i) {        // arinit: row r=e+8i+4h
            #pragma unroll
            for (int e = 0; e < 4; ++e) {
                const int r = e + 8*i + 4*h;
                r16.f[4*i+e] = (r < 3) ? b_rgb2[r] : ((r == 3) ? b_sigma[0] : 0.0f);
            }
        }
        #pragma unroll
        for (int i = 0; i < 4; ++i) tbl[(R_ARI+i)*64 + lane] = r16.u[i];
    }
}

// ---------------------------------------------------------------------------
// FUSED kernel: one block = 8 consecutive rays = one contiguous sample range
// (ray_ids = repeat(arange, counts) -> consecutive rays' samples are
// contiguous). Phase 1: 4 waves cooperatively run the verified 32x32x16 MFMA
// MLP over ceil(total/32) tiles, results to LDS (no global round-trip).
// Phase 2: each wave scans+reduces 2 rays from LDS, writes 3 floats/ray.
// Removes: 16 MB smp write + 16 MB read + render kernel launch.
// ---------------------------------------------------------------------------
__global__ __launch_bounds__(256) void nerf_fused(
    const float* __restrict__ samples,   // (N_SAMPLES, 7)
    const int*   __restrict__ packing,   // (N_RAYS, 2): start, count
    const uint4* __restrict__ tbl,       // [26][64] frag table
    const float* __restrict__ bg,        // (3)
    float*       __restrict__ out)       // (N_RAYS, 3)
{
    __shared__ uint4  wlds[NREC * 64];   // 26.6 KB weight frags
    __shared__ float4 obuf[MAXS];        // 7.4 KB per-sample {tau, r, g, b}

    for (int i = threadIdx.x; i < NREC * 64; i += 256) wlds[i] = tbl[i];

    const int lane = threadIdx.x & 63;
    const int m32  = lane & 31;
    const int h    = lane >> 5;
    const int wid  = threadIdx.x >> 6;
    const int ray0 = blockIdx.x * RPB;

    // block's contiguous sample range (wave-uniform scalar loads)
    const int start0 = packing[2 * ray0];
    int total = 0;
    #pragma unroll
    for (int i = 0; i < RPB; ++i) total += packing[2 * (ray0 + i) + 1];

    __syncthreads();

    const uint4* wl = &wlds[lane];
    #define LDW(rec) ({ RecU r_; r_.u = wl[(rec)*64]; r_.v; })

    const f32x16 zero16 = {0,0,0,0,0,0,0,0,0,0,0,0,0,0,0,0};
    const int ntiles = (total + 31) >> 5;

    // ---- Phase 1: MLP tiles, wave-strided ----
    for (int t = wid; t < ntiles; t += 4) {
        const int sidx  = 32 * t + m32;               // block-local sample idx
        const int cl    = (sidx < total) ? sidx : (total - 1);  // clamped
        const float* sp = samples + (size_t)(start0 + cl) * 7;
        const f4a sa = *(const f4a*)sp;
        const f4a sb = *(const f4a*)(sp + 3);

        // merged input kstep: h=0 lanes pos+1, h=1 lanes dirs+1 (q4-7 unused)
        FragU bin;
        bin.h2[0] = pk2(h ? sb.x : sa.x, h ? sb.y : sa.y);
        bin.h2[1] = pk2(h ? sb.z : sa.z, 1.0f);
        bin.w[2] = 0; bin.w[3] = 0;

        // layer1: two independent M=32 halves
        bf16x8 B2c[4];
        {
            f32x16 a0 = __builtin_amdgcn_mfma_f32_32x32x16_bf16(LDW(R_A1+0), bin.v, zero16, 0,0,0);
            f32x16 a1 = __builtin_amdgcn_mfma_f32_32x32x16_bf16(LDW(R_A1+1), bin.v, zero16, 0,0,0);
            B2c[0] = packB_relu<0>(a0);
            B2c[1] = packB_relu<8>(a0);
            B2c[2] = packB_relu<0>(a1);
            B2c[3] = packB_relu<8>(a1);
        }

        // layer2: two parallel 2-deep trees + combine in pack
        bf16x8 Bf0, Bf1;
        {
            Rec16U rc;
            #pragma unroll
            for (int i = 0; i < 4; ++i) rc.u[i] = wl[(R_B2I+i)*64];
            f32x16 u0, u1;
            u0 = __builtin_amdgcn_mfma_f32_32x32x16_bf16(LDW(R_A2+0), B2c[0], rc.v, 0,0,0);
            u1 = __builtin_amdgcn_mfma_f32_32x32x16_bf16(LDW(R_A2+2), B2c[2], zero16, 0,0,0);
            u0 = __builtin_amdgcn_mfma_f32_32x32x16_bf16(LDW(R_A2+1), B2c[1], u0, 0,0,0);
            u1 = __builtin_amdgcn_mfma_f32_32x32x16_bf16(LDW(R_A2+3), B2c[3], u1, 0,0,0);
            Bf0 = packB_plain2<0>(u0, u1);
            Bf1 = packB_plain2<8>(u0, u1);
        }

        // rgb1: per half, (2-deep feats tree) || (1-deep dirs branch)
        bf16x8 Bh[4];
        {
            f32x16 p0, p1, q0, q1;
            q0 = __builtin_amdgcn_mfma_f32_32x32x16_bf16(LDW(R_R1B+0), bin.v, zero16, 0,0,0);
            q1 = __builtin_amdgcn_mfma_f32_32x32x16_bf16(LDW(R_R1B+1), bin.v, zero16, 0,0,0);
            p0 = __builtin_amdgcn_mfma_f32_32x32x16_bf16(LDW(R_R1A+0), Bf0, zero16, 0,0,0);
            p1 = __builtin_amdgcn_mfma_f32_32x32x16_bf16(LDW(R_R1A+2), Bf0, zero16, 0,0,0);
            p0 = __builtin_amdgcn_mfma_f32_32x32x16_bf16(LDW(R_R1A+1), Bf1, p0, 0,0,0);
            p1 = __builtin_amdgcn_mfma_f32_32x32x16_bf16(LDW(R_R1A+3), Bf1, p1, 0,0,0);
            Bh[0] = packB_relu2<0>(p0, q0);
            Bh[1] = packB_relu2<8>(p0, q0);
            Bh[2] = packB_relu2<0>(p1, q1);
            Bh[3] = packB_relu2<8>(p1, q1);
        }

        // rgb2 rows 0-2 + sigma row 3: three parallel 2-deep trees
        float ar0, ar1, ar2, ar3;
        {
            Rec16U rc;
            #pragma unroll
            for (int i = 0; i < 4; ++i) rc.u[i] = wl[(R_ARI+i)*64];
            f32x16 x, y, z;
            x = __builtin_amdgcn_mfma_f32_32x32x16_bf16(LDW(R_AR2F+0), Bf0, rc.v, 0,0,0);
            y = __builtin_amdgcn_mfma_f32_32x32x16_bf16(LDW(R_AR2+0), Bh[0], zero16, 0,0,0);
            z = __builtin_amdgcn_mfma_f32_32x32x16_bf16(LDW(R_AR2+2), Bh[2], zero16, 0,0,0);
            x = __builtin_amdgcn_mfma_f32_32x32x16_bf16(LDW(R_AR2F+1), Bf1, x, 0,0,0);
            y = __builtin_amdgcn_mfma_f32_32x32x16_bf16(LDW(R_AR2+1), Bh[1], y, 0,0,0);
            z = __builtin_amdgcn_mfma_f32_32x32x16_bf16(LDW(R_AR2+3), Bh[3], z, 0,0,0);
            ar0 = x[0] + y[0] + z[0];
            ar1 = x[1] + y[1] + z[1];
            ar2 = x[2] + y[2] + z[2];
            ar3 = x[3] + y[3] + z[3];
        }

        const float rr    = sigmoid_fast(ar0);
        const float gg    = sigmoid_fast(ar1);
        const float bb    = sigmoid_fast(ar2);
        const float sigma = softplus_fast(ar3);
        const float tau   = sigma * sb.w;
        if (lane < 32 && sidx < total)
            obuf[sidx] = make_float4(tau, rr, gg, bb);
    }
    #undef LDW

    __syncthreads();

    // ---- Phase 2: per-ray scan + composite (2 rays per wave) ----
    const float bg0 = bg[0], bg1 = bg[1], bg2 = bg[2];
    #pragma unroll
    for (int ri = 0; ri < 2; ++ri) {
        const int ray   = ray0 + wid * 2 + ri;
        const int rs    = packing[2 * ray] - start0;   // LDS-local start
        const int count = packing[2 * ray + 1];

        float tau = 0.0f, r = 0.0f, g = 0.0f, b = 0.0f;
        if (lane < count) {
            const float4 v = obuf[rs + lane];
            tau = v.x; r = v.y; g = v.z; b = v.w;
        }

        float incl = tau;
        #pragma unroll
        for (int off = 1; off < 64; off <<= 1) {
            const float v = __shfl_up(incl, off, 64);
            if (lane >= off) incl += v;
        }
        const float c_excl = incl - tau;

        const float T     = __expf(-c_excl);
        const float alpha = 1.0f - __expf(-tau);
        float w = (lane < count && T > THRESH) ? T * alpha : 0.0f;

        float cr = r * w, cg = g * w, cb = b * w;
        #pragma unroll
        for (int off = 32; off > 0; off >>= 1) {
            cr += __shfl_down(cr, off, 64);
            cg += __shfl_down(cg, off, 64);
            cb += __shfl_down(cb, off, 64);
            w  += __shfl_down(w,  off, 64);
        }

        if (lane == 0) {
            out[ray * 3 + 0] = cr + bg0 * (1.0f - w);
            out[ray * 3 + 1] = cg + bg1 * (1.0f - w);
            out[ray * 3 + 2] = cb + bg2 * (1.0f - w);
        }
    }
}

extern "C" void kernel_launch(void* const* d_in, const int* in_sizes, int n_in,
                              void* d_out, int out_size, void* d_ws, size_t ws_size,
                              hipStream_t stream) {
    const float* samples  = (const float*)d_in[0];
    const int*   packing  = (const int*)  d_in[1];
    const float* w1       = (const float*)d_in[3];
    const float* b1       = (const float*)d_in[4];
    const float* w2       = (const float*)d_in[5];
    const float* b2       = (const float*)d_in[6];
    const float* w_sigma  = (const float*)d_in[7];
    const float* b_sigma  = (const float*)d_in[8];
    const float* w_rgb1   = (const float*)d_in[9];
    const float* b_rgb1   = (const float*)d_in[10];
    const float* w_rgb2   = (const float*)d_in[11];
    const float* b_rgb2   = (const float*)d_in[12];
    const float* bg       = (const float*)d_in[13];

    uint4* tbl = (uint4*)d_ws;           // 26x64x16B frag table
    float* out = (float*)d_out;

    nerf_build_frags<<<1, 256, 0, stream>>>(
        w1, b1, w2, b2, w_sigma, b_sigma,
        w_rgb1, b_rgb1, w_rgb2, b_rgb2, tbl);

    // one block per 8 consecutive rays (contiguous sample range)
    nerf_fused<<<N_RAYS / RPB, 256, 0, stream>>>(samples, packing, tbl, bg, out);
}

// Round 18
// 45.097 us; speedup vs baseline: 1.5659x; 1.5659x over previous
//
#include <hip/hip_runtime.h>
#include <hip/hip_bf16.h>
#include <math.h>
#include <stdint.h>

#define N_RAYS    32768
#define N_SAMPLES (N_RAYS * 32)
#define THRESH 0.0001f
#define TBL_OFF  (16u * 1024u * 1024u)   // frag table after smp[] in d_ws

// record ids in frag table (one uint4 per lane per record)
#define R_A1   0   // +t (2)
#define R_A2   2   // +c (4)
#define R_R1A  6   // +2t+c (4)
#define R_R1B  10  // +t (2)
#define R_AR2  12  // +c (4)
#define R_AR2F 16  // +c (2)
#define R_B2I  18  // +i (4)
#define R_ARI  22  // +i (4)   -> 26 records total

typedef __attribute__((ext_vector_type(8)))  __bf16 bf16x8;
typedef __attribute__((ext_vector_type(16))) float  f32x16;
typedef float f4a __attribute__((ext_vector_type(4), aligned(4)));

union FragU  { __hip_bfloat162 h2[4]; uint32_t w[4]; bf16x8 v; };
union RecU   { bf16x8 v; uint4 u; };
union Rec16U { f32x16 v; uint4 u[4]; float f[16]; };
union H2U    { __hip_bfloat162 h; uint32_t u; };

__device__ inline __hip_bfloat162 pk2(float lo, float hi) {
    float2 t; t.x = lo; t.y = hi;
    return __float22bfloat162_rn(t);
}

__device__ inline bf16x8 pack8(const float* vals) {
    FragU u;
    u.h2[0] = pk2(vals[0], vals[1]);
    u.h2[1] = pk2(vals[2], vals[3]);
    u.h2[2] = pk2(vals[4], vals[5]);
    u.h2[3] = pk2(vals[6], vals[7]);
    return u.v;
}

__device__ inline float rcp_fast(float x) {
    float r;
    asm("v_rcp_f32 %0, %1" : "=v"(r) : "v"(x));
    return r;
}
__device__ inline float sigmoid_fast(float x) { return rcp_fast(1.0f + __expf(-x)); }
__device__ inline float softplus_fast(float x) {
    const float e = __expf(-fabsf(x));
    return fmaxf(x, 0.0f) + __logf(1.0f + e);
}

template <int P>
__device__ inline bf16x8 packB_relu(f32x16 a) {
    FragU u;
    u.h2[0] = pk2(fmaxf(a[P+0],0.f), fmaxf(a[P+1],0.f));
    u.h2[1] = pk2(fmaxf(a[P+2],0.f), fmaxf(a[P+3],0.f));
    u.h2[2] = pk2(fmaxf(a[P+4],0.f), fmaxf(a[P+5],0.f));
    u.h2[3] = pk2(fmaxf(a[P+6],0.f), fmaxf(a[P+7],0.f));
    return u.v;
}
template <int P>
__device__ inline bf16x8 packB_plain(f32x16 a) {
    FragU u;
    u.h2[0] = pk2(a[P+0], a[P+1]);
    u.h2[1] = pk2(a[P+2], a[P+3]);
    u.h2[2] = pk2(a[P+4], a[P+5]);
    u.h2[3] = pk2(a[P+6], a[P+7]);
    return u.v;
}

// ---------------------------------------------------------------------------
// Setup kernel: per-lane weight fragments for the 32x32x16 path (verified
// rounds 12-16). D layout: col=lane&31, row=(reg&3)+8*(reg>>2)+4*(lane>>5);
// rr(q,h) = (q&3)+8*(q>>2)+4*h.
// ---------------------------------------------------------------------------
__global__ __launch_bounds__(256) void nerf_build_frags(
    const float* __restrict__ w1,  const float* __restrict__ b1,
    const float* __restrict__ w2,  const float* __restrict__ b2,
    const float* __restrict__ w_sigma, const float* __restrict__ b_sigma,
    const float* __restrict__ w_rgb1,  const float* __restrict__ b_rgb1,
    const float* __restrict__ w_rgb2,  const float* __restrict__ b_rgb2,
    uint4* __restrict__ tbl)
{
    const int wid  = threadIdx.x >> 6;
    const int lane = threadIdx.x & 63;
    const int m    = lane & 31;
    const int h    = lane >> 5;
    RecU rec;

    if (wid == 0) {
        #pragma unroll
        for (int t = 0; t < 2; ++t) {        // A1: rows j=32t+m; k slots h=0,q0..3
            float v[8] = {0,0,0,0,0,0,0,0};
            if (h == 0) {
                const int j = 32*t + m;
                v[0] = w1[j]; v[1] = w1[64+j]; v[2] = w1[128+j]; v[3] = b1[j];
            }
            rec.v = pack8(v); tbl[(R_A1+t)*64 + lane] = rec.u;
        }
        #pragma unroll
        for (int c = 0; c < 4; ++c) {        // A2: A[f=m][j=16c+rr(q,h)] = w2[j*32+f]
            float v[8];
            #pragma unroll
            for (int q = 0; q < 8; ++q) {
                const int j = 16*c + (q&3) + 8*(q>>2) + 4*h;
                v[q] = w2[j*32 + m];
            }
            rec.v = pack8(v); tbl[(R_A2+c)*64 + lane] = rec.u;
        }
    } else if (wid == 1) {
        #pragma unroll
        for (int t = 0; t < 2; ++t)          // Ar1a: rows j=32t+m; k=f=16c+rr
            #pragma unroll
            for (int c = 0; c < 2; ++c) {
                float v[8];
                #pragma unroll
                for (int q = 0; q < 8; ++q) {
                    const int f = 16*c + (q&3) + 8*(q>>2) + 4*h;
                    v[q] = w_rgb1[f*64 + 32*t + m];
                }
                rec.v = pack8(v); tbl[(R_R1A+2*t+c)*64 + lane] = rec.u;
            }
        #pragma unroll
        for (int t = 0; t < 2; ++t) {        // Ar1b: dirs+bias on h=1 slots q0..3
            float v[8] = {0,0,0,0,0,0,0,0};
            if (h == 1) {
                const int j = 32*t + m;
                v[0] = w_rgb1[32*64 + j]; v[1] = w_rgb1[33*64 + j];
                v[2] = w_rgb1[34*64 + j]; v[3] = b_rgb1[j];
            }
            rec.v = pack8(v); tbl[(R_R1B+t)*64 + lane] = rec.u;
        }
    } else if (wid == 2) {
        #pragma unroll
        for (int c = 0; c < 4; ++c) {        // Ar2: rows m=0..2 rgb; k=hh=16c+rr
            float v[8];
            #pragma unroll
            for (int q = 0; q < 8; ++q) {
                const int hh = 16*c + (q&3) + 8*(q>>2) + 4*h;
                v[q] = (m < 3) ? w_rgb2[hh*3 + m] : 0.0f;
            }
            rec.v = pack8(v); tbl[(R_AR2+c)*64 + lane] = rec.u;
        }
        #pragma unroll
        for (int c = 0; c < 2; ++c) {        // Ar2f: w_sigma on row m=3; k=f=16c+rr
            float v[8];
            #pragma unroll
            for (int q = 0; q < 8; ++q) {
                const int f = 16*c + (q&3) + 8*(q>>2) + 4*h;
                v[q] = (m == 3) ? w_sigma[f] : 0.0f;
            }
            rec.v = pack8(v); tbl[(R_AR2F+c)*64 + lane] = rec.u;
        }
        Rec16U r16;
        #pragma unroll
        for (int i = 0; i < 4; ++i) {        // b2i: C-init, reg=4i+e -> b2[e+8i+4h]
            #pragma unroll
            for (int e = 0; e < 4; ++e) r16.f[4*i+e] = b2[e + 8*i + 4*h];
        }
        #pragma unroll
        for (int i = 0; i < 4; ++i) tbl[(R_B2I+i)*64 + lane] = r16.u[i];
        #pragma unroll
        for (int i = 0; i < 4; ++i) {        // arinit: row r=e+8i+4h
            #pragma unroll
            for (int e = 0; e < 4; ++e) {
                const int r = e + 8*i + 4*h;
                r16.f[4*i+e] = (r < 3) ? b_rgb2[r] : ((r == 3) ? b_sigma[0] : 0.0f);
            }
        }
        #pragma unroll
        for (int i = 0; i < 4; ++i) tbl[(R_ARI+i)*64 + lane] = r16.u[i];
    }
}

// ---------------------------------------------------------------------------
// Main MFMA MLP, 32x32x16, DUAL-STREAM (round-13 structure — best measured).
// One wave = 4 pairs of independent 32-sample tiles, lock-step interleaved.
// Output record packed as 4x bf16 {tau, r, g, b} = 8 B (halves smp traffic).
// ---------------------------------------------------------------------------
__global__ __launch_bounds__(256, 2) void nerf_mlp_mfma(
    const float* __restrict__ samples,   // (N_SAMPLES, 7)
    const uint4* __restrict__ tbl,       // [26][64] frag table
    uint2* __restrict__ out)             // (N_SAMPLES): bf16x4 {tau, r, g, b}
{
    const int lane = threadIdx.x & 63;
    const int m32  = lane & 31;
    const int h    = lane >> 5;
    const int wgid = (blockIdx.x * blockDim.x + threadIdx.x) >> 6;  // 0..4095
    const int base0 = wgid * 256;        // 4 pairs x 64 samples

    // ---- pair-0 sample loads first (2-deep rotating buffers)
    f4a sa[2][2], sb[2][2];
    {
        const float* sp0 = samples + (size_t)(base0 + m32) * 7;
        const float* sp1 = samples + (size_t)(base0 + 32 + m32) * 7;
        sa[0][0] = *(const f4a*)sp0;  sb[0][0] = *(const f4a*)(sp0 + 3);
        sa[0][1] = *(const f4a*)sp1;  sb[0][1] = *(const f4a*)(sp1 + 3);
    }

    // ---- coalesced fragment loads
    bf16x8 A1[2], A2[4], R1a[4], R1b[2], Ar2[4], Ar2f[2];
    f32x16 b2i, arinit;
    {
        RecU r_;
        #pragma unroll
        for (int t = 0; t < 2; ++t) { r_.u = tbl[(R_A1+t)*64 + lane];  A1[t]  = r_.v; }
        #pragma unroll
        for (int c = 0; c < 4; ++c) { r_.u = tbl[(R_A2+c)*64 + lane];  A2[c]  = r_.v; }
        #pragma unroll
        for (int i = 0; i < 4; ++i) { r_.u = tbl[(R_R1A+i)*64 + lane]; R1a[i] = r_.v; }
        #pragma unroll
        for (int t = 0; t < 2; ++t) { r_.u = tbl[(R_R1B+t)*64 + lane]; R1b[t] = r_.v; }
        #pragma unroll
        for (int c = 0; c < 4; ++c) { r_.u = tbl[(R_AR2+c)*64 + lane]; Ar2[c] = r_.v; }
        #pragma unroll
        for (int c = 0; c < 2; ++c) { r_.u = tbl[(R_AR2F+c)*64 + lane]; Ar2f[c] = r_.v; }
        Rec16U r16;
        #pragma unroll
        for (int i = 0; i < 4; ++i) r16.u[i] = tbl[(R_B2I+i)*64 + lane];
        b2i = r16.v;
        #pragma unroll
        for (int i = 0; i < 4; ++i) r16.u[i] = tbl[(R_ARI+i)*64 + lane];
        arinit = r16.v;
    }

    const f32x16 zero16 = {0,0,0,0,0,0,0,0,0,0,0,0,0,0,0,0};

    #pragma unroll
    for (int it = 0; it < 4; ++it) {
        const int cb = it & 1;
        const int nb = (it + 1) & 1;
        if (it < 3) {                    // prefetch next pair
            const int nbase = base0 + (it + 1) * 64;
            const float* sp0 = samples + (size_t)(nbase + m32) * 7;
            const float* sp1 = samples + (size_t)(nbase + 32 + m32) * 7;
            sa[nb][0] = *(const f4a*)sp0;  sb[nb][0] = *(const f4a*)(sp0 + 3);
            sa[nb][1] = *(const f4a*)sp1;  sb[nb][1] = *(const f4a*)(sp1 + 3);
        }

        // merged input kstep per stream: h=0 lanes pos+1, h=1 lanes dirs+1
        FragU bin[2];
        #pragma unroll
        for (int s = 0; s < 2; ++s) {
            bin[s].h2[0] = pk2(h ? sb[cb][s].x : sa[cb][s].x,
                               h ? sb[cb][s].y : sa[cb][s].y);
            bin[s].h2[1] = pk2(h ? sb[cb][s].z : sa[cb][s].z, 1.0f);
            bin[s].w[2] = 0; bin[s].w[3] = 0;
        }

        // layer1: 2 tiles x 2 streams (4 independent MFMAs)
        f32x16 accL1[2][2];
        #pragma unroll
        for (int t = 0; t < 2; ++t)
            #pragma unroll
            for (int s = 0; s < 2; ++s)
                accL1[s][t] = __builtin_amdgcn_mfma_f32_32x32x16_bf16(A1[t], bin[s].v, zero16, 0,0,0);

        bf16x8 B2c[2][4];
        #pragma unroll
        for (int s = 0; s < 2; ++s) {
            B2c[s][0] = packB_relu<0>(accL1[s][0]);
            B2c[s][1] = packB_relu<8>(accL1[s][0]);
            B2c[s][2] = packB_relu<0>(accL1[s][1]);
            B2c[s][3] = packB_relu<8>(accL1[s][1]);
        }

        // layer2: 4-kstep chain per stream, streams interleaved
        f32x16 accL2[2];
        #pragma unroll
        for (int s = 0; s < 2; ++s)
            accL2[s] = __builtin_amdgcn_mfma_f32_32x32x16_bf16(A2[0], B2c[s][0], b2i, 0,0,0);
        #pragma unroll
        for (int c = 1; c < 4; ++c)
            #pragma unroll
            for (int s = 0; s < 2; ++s)
                accL2[s] = __builtin_amdgcn_mfma_f32_32x32x16_bf16(A2[c], B2c[s][c], accL2[s], 0,0,0);

        bf16x8 Bf[2][2];
        #pragma unroll
        for (int s = 0; s < 2; ++s) {
            Bf[s][0] = packB_plain<0>(accL2[s]);
            Bf[s][1] = packB_plain<8>(accL2[s]);
        }

        // rgb1: 2 tiles x 2 streams, 3-deep chains interleaved
        f32x16 ah[2][2];
        #pragma unroll
        for (int t = 0; t < 2; ++t)
            #pragma unroll
            for (int s = 0; s < 2; ++s) {
                ah[s][t] = __builtin_amdgcn_mfma_f32_32x32x16_bf16(R1a[2*t+0], Bf[s][0], zero16, 0,0,0);
                ah[s][t] = __builtin_amdgcn_mfma_f32_32x32x16_bf16(R1a[2*t+1], Bf[s][1], ah[s][t], 0,0,0);
                ah[s][t] = __builtin_amdgcn_mfma_f32_32x32x16_bf16(R1b[t],     bin[s].v, ah[s][t], 0,0,0);
            }

        bf16x8 Bh[2][4];
        #pragma unroll
        for (int s = 0; s < 2; ++s) {
            Bh[s][0] = packB_relu<0>(ah[s][0]);
            Bh[s][1] = packB_relu<8>(ah[s][0]);
            Bh[s][2] = packB_relu<0>(ah[s][1]);
            Bh[s][3] = packB_relu<8>(ah[s][1]);
        }

        // rgb2 (+sigma row 3): 6-kstep chain per stream, interleaved
        f32x16 ar[2];
        #pragma unroll
        for (int s = 0; s < 2; ++s)
            ar[s] = __builtin_amdgcn_mfma_f32_32x32x16_bf16(Ar2[0], Bh[s][0], arinit, 0,0,0);
        #pragma unroll
        for (int c = 1; c < 4; ++c)
            #pragma unroll
            for (int s = 0; s < 2; ++s)
                ar[s] = __builtin_amdgcn_mfma_f32_32x32x16_bf16(Ar2[c], Bh[s][c], ar[s], 0,0,0);
        #pragma unroll
        for (int c = 0; c < 2; ++c)
            #pragma unroll
            for (int s = 0; s < 2; ++s)
                ar[s] = __builtin_amdgcn_mfma_f32_32x32x16_bf16(Ar2f[c], Bf[s][c], ar[s], 0,0,0);

        #pragma unroll
        for (int s = 0; s < 2; ++s) {
            const float rr    = sigmoid_fast(ar[s][0]);
            const float gg    = sigmoid_fast(ar[s][1]);
            const float bb    = sigmoid_fast(ar[s][2]);
            const float sigma = softplus_fast(ar[s][3]);
            const float tau   = sigma * sb[cb][s].w;
            if (lane < 32) {
                H2U lo, hi;
                lo.h = pk2(tau, rr);
                hi.h = pk2(gg, bb);
                out[base0 + it * 64 + s * 32 + m32] = make_uint2(lo.u, hi.u);
            }
        }
    }
}

// ---------------------------------------------------------------------------
// Kernel 2: one wave per ray — scan tau, gate, reduce (bf16x4 input records).
// ---------------------------------------------------------------------------
__global__ __launch_bounds__(256) void nerf_render_kernel(
    const uint2* __restrict__ smp,       // (N_SAMPLES): bf16x4 {tau, r, g, b}
    const int*   __restrict__ packing,
    const float* __restrict__ bg,
    float*       __restrict__ out)
{
    const int gtid = blockIdx.x * blockDim.x + threadIdx.x;
    const int ray  = gtid >> 6;
    const int lane = threadIdx.x & 63;
    if (ray >= N_RAYS) return;

    const int start = packing[2 * ray];
    const int count = packing[2 * ray + 1];

    float tau = 0.0f, r = 0.0f, g = 0.0f, b = 0.0f;
    if (lane < count) {
        const uint2 v = smp[start + lane];
        H2U lo, hi;
        lo.u = v.x; hi.u = v.y;
        tau = __bfloat162float(lo.h.x); r = __bfloat162float(lo.h.y);
        g   = __bfloat162float(hi.h.x); b = __bfloat162float(hi.h.y);
    }

    float incl = tau;
    #pragma unroll
    for (int off = 1; off < 64; off <<= 1) {
        const float v = __shfl_up(incl, off, 64);
        if (lane >= off) incl += v;
    }
    const float c_excl = incl - tau;

    const float T     = __expf(-c_excl);
    const float alpha = 1.0f - __expf(-tau);
    float w = (lane < count && T > THRESH) ? T * alpha : 0.0f;

    float cr = r * w, cg = g * w, cb = b * w;

    #pragma unroll
    for (int off = 32; off > 0; off >>= 1) {
        cr += __shfl_down(cr, off, 64);
        cg += __shfl_down(cg, off, 64);
        cb += __shfl_down(cb, off, 64);
        w  += __shfl_down(w,  off, 64);
    }

    if (lane == 0) {
        out[ray * 3 + 0] = cr + bg[0] * (1.0f - w);
        out[ray * 3 + 1] = cg + bg[1] * (1.0f - w);
        out[ray * 3 + 2] = cb + bg[2] * (1.0f - w);
    }
}

extern "C" void kernel_launch(void* const* d_in, const int* in_sizes, int n_in,
                              void* d_out, int out_size, void* d_ws, size_t ws_size,
                              hipStream_t stream) {
    const float* samples  = (const float*)d_in[0];
    const int*   packing  = (const int*)  d_in[1];
    const float* w1       = (const float*)d_in[3];
    const float* b1       = (const float*)d_in[4];
    const float* w2       = (const float*)d_in[5];
    const float* b2       = (const float*)d_in[6];
    const float* w_sigma  = (const float*)d_in[7];
    const float* b_sigma  = (const float*)d_in[8];
    const float* w_rgb1   = (const float*)d_in[9];
    const float* b_rgb1   = (const float*)d_in[10];
    const float* w_rgb2   = (const float*)d_in[11];
    const float* b_rgb2   = (const float*)d_in[12];
    const float* bg       = (const float*)d_in[13];

    uint2* smp = (uint2*)d_ws;                           // 8 MiB (bf16x4/sample)
    uint4* tbl = (uint4*)((char*)d_ws + TBL_OFF);        // 26x64x16B frag table
    float* out = (float*)d_out;

    nerf_build_frags<<<1, 256, 0, stream>>>(
        w1, b1, w2, b2, w_sigma, b_sigma,
        w_rgb1, b_rgb1, w_rgb2, b_rgb2, tbl);

    // 1024 blocks x 4 waves = 4096 waves x 4 pairs x 64 samples = N_SAMPLES
    nerf_mlp_mfma<<<1024, 256, 0, stream>>>(samples, tbl, smp);

    nerf_render_kernel<<<(N_RAYS * 64) / 256, 256, 0, stream>>>(smp, packing, bg, out);
}